// Round 1
// baseline (2528.288 us; speedup 1.0000x reference)
//
#include <hip/hip_runtime.h>

#define RADIUS 3
#define PP 3
#define C_CH 128
#define N_FR 16
#define H0 120
#define W0 160
#define H1 30
#define W1 40

// 4x4 average pool: fm0 [N,C,120,160] -> fm1 [N,C,30,40]
__global__ void pool_kernel(const float* __restrict__ fm0, float* __restrict__ fm1) {
    int idx = blockIdx.x * blockDim.x + threadIdx.x;
    int total = N_FR * C_CH * H1 * W1;
    if (idx >= total) return;
    int x = idx % W1;
    int y = (idx / W1) % H1;
    int nc = idx / (W1 * H1);
    const float* src = fm0 + ((size_t)nc * H0 + y * 4) * W0 + x * 4;
    float s = 0.f;
#pragma unroll
    for (int dy = 0; dy < 4; ++dy) {
#pragma unroll
        for (int dx = 0; dx < 4; ++dx) s += src[dy * W0 + dx];
    }
    fm1[idx] = s * (1.f / 16.f);
}

// One wave (64 lanes) per (edge, patch-pos, level). Lane (a,b) = 8x8 window cell.
__global__ __launch_bounds__(64) void corr_kernel(
        const float* __restrict__ fmap,   // [N,C,H0,W0]
        const float* __restrict__ fm1,    // [N,C,H1,W1]
        const float* __restrict__ gmap,   // [M,C,3,3]
        const float* __restrict__ coords, // [E,3,3,2]
        const int* __restrict__ ii,
        const int* __restrict__ jj,
        float* __restrict__ out) {        // [E, 7,7,3,3,2]
    int e = blockIdx.x;
    int pq = blockIdx.y;           // p*3+q
    int lvl = blockIdx.z;
    int p = pq / 3, q = pq % 3;
    int lane = threadIdx.x;        // 0..63
    int a = lane >> 3, b = lane & 7;

    int Hl = lvl ? H1 : H0;
    int Wl = lvl ? W1 : W0;
    float scale = lvl ? 0.25f : 1.0f;
    const float* fm = lvl ? fm1 : fmap;

    const float* cptr = coords + (((size_t)e * PP + p) * PP + q) * 2;
    float x = cptr[0] * scale;
    float y = cptr[1] * scale;
    float x0 = floorf(x), y0 = floorf(y);
    float fx = x - x0, fy = y - y0;
    int x0i = (int)x0, y0i = (int)y0;

    int gy = y0i + a - RADIUS;
    gy = min(max(gy, 0), Hl - 1);
    int gx = x0i + b - RADIUS;
    gx = min(max(gx, 0), Wl - 1);

    int jje = jj[e];
    int iie = ii[e];

    __shared__ float gsm[C_CH];
    __shared__ float cw[8][8];

    // stage the gm channel column for this (p,q) into LDS
    const float* gbase = gmap + (size_t)iie * C_CH * 9 + pq;
    gsm[lane]      = gbase[(size_t)lane * 9];
    gsm[lane + 64] = gbase[(size_t)(lane + 64) * 9];
    __syncthreads();

    const float* fptr = fm + ((size_t)jje * C_CH * Hl + gy) * Wl + gx;
    const size_t cstride = (size_t)Hl * Wl;
    float acc = 0.f;
#pragma unroll 8
    for (int c = 0; c < C_CH; ++c) {
        acc += fptr[c * cstride] * gsm[c];
    }
    cw[a][b] = acc;
    __syncthreads();

    if (a < 7 && b < 7) {
        float w00 = (1.f - fy) * (1.f - fx);
        float w01 = (1.f - fy) * fx;
        float w10 = fy * (1.f - fx);
        float w11 = fy * fx;
        float v = w00 * cw[a][b] + w01 * cw[a][b + 1]
                + w10 * cw[a + 1][b] + w11 * cw[a + 1][b + 1];
        // out[e][a][b][p][q][lvl]
        size_t oidx = (size_t)e * 882 + (size_t)((a * 7 + b) * 9 + pq) * 2 + lvl;
        out[oidx] = v;
    }
}

extern "C" void kernel_launch(void* const* d_in, const int* in_sizes, int n_in,
                              void* d_out, int out_size, void* d_ws, size_t ws_size,
                              hipStream_t stream) {
    const float* fmap   = (const float*)d_in[0];
    const float* gmap   = (const float*)d_in[1];
    const float* coords = (const float*)d_in[2];
    const int* ii       = (const int*)d_in[3];
    const int* jj       = (const int*)d_in[4];
    float* out = (float*)d_out;
    float* fm1 = (float*)d_ws;   // N*C*H1*W1 floats = 9.83 MB

    int E = in_sizes[3];

    int total1 = N_FR * C_CH * H1 * W1;
    pool_kernel<<<(total1 + 255) / 256, 256, 0, stream>>>(fmap, fm1);
    corr_kernel<<<dim3(E, 9, 2), 64, 0, stream>>>(fmap, fm1, gmap, coords, ii, jj, out);
}

// Round 2
// 460.370 us; speedup vs baseline: 5.4919x; 5.4919x over previous
//
#include <hip/hip_runtime.h>

#define RADIUS 3
#define PP 3
#define C_CH 128
#define N_FR 16
#define H0 120
#define W0 160
#define H1 30
#define W1 40

#define EXT 10            // union window extent (10x10 covers all 9 shifted 8x8 supports)
#define NCELL (EXT*EXT)   // 100
#define CSTR 132          // cell stride in dwords: 33 16B-chunks (odd -> conflict-free b128)

// 4x4 average pool: fm0 [N,C,120,160] -> fm1 [N,C,30,40]
__global__ void pool_kernel(const float* __restrict__ fm0, float* __restrict__ fm1) {
    int idx = blockIdx.x * blockDim.x + threadIdx.x;
    int total = N_FR * C_CH * H1 * W1;
    if (idx >= total) return;
    int x = idx % W1;
    int y = (idx / W1) % H1;
    int nc = idx / (W1 * H1);
    const float* src = fm0 + ((size_t)nc * H0 + y * 4) * W0 + x * 4;
    float s = 0.f;
#pragma unroll
    for (int dy = 0; dy < 4; ++dy) {
        float4 v = *reinterpret_cast<const float4*>(src + dy * W0);
        s += v.x + v.y + v.z + v.w;
    }
    fm1[idx] = s * (1.f / 16.f);
}

// One block per (edge, level). 576 threads = 9 waves; wave w handles patch-pos pq=w.
__global__ __launch_bounds__(576) void corr_kernel(
        const float* __restrict__ fmap,   // [N,C,H0,W0]
        const float* __restrict__ fm1,    // [N,C,H1,W1]
        const float* __restrict__ gmap,   // [M,C,3,3]
        const float* __restrict__ coords, // [E,3,3,2]
        const int* __restrict__ ii,
        const int* __restrict__ jj,
        float* __restrict__ out) {        // [E,7,7,3,3,2]
    __shared__ float sfm[NCELL * CSTR];   // [cell][c], stride 132
    __shared__ float sg[9 * CSTR];        // [pq][c]

    int e = blockIdx.x;
    int lvl = blockIdx.y;
    int tid = threadIdx.x;
    int wave = tid >> 6, lane = tid & 63;

    int Hl = lvl ? H1 : H0;
    int Wl = lvl ? W1 : W0;
    float scale = lvl ? 0.25f : 1.0f;
    const float* fm = lvl ? fm1 : fmap;

    int iie = ii[e];
    int jje = jj[e];
    const float* cb = coords + (size_t)e * 18;

    // union window base: coords[e][0][0] is the (x,y)-minimum by construction
    int bx = (int)floorf(cb[0] * scale) - RADIUS;
    int by = (int)floorf(cb[1] * scale) - RADIUS;

    // ---- stage fm union window: [cell][c], 4 channels per thread, b128 writes ----
    const float* fbase = fm + (size_t)jje * C_CH * Hl * Wl;
    const size_t hw = (size_t)Hl * Wl;
    for (int idx = tid; idx < NCELL * (C_CH / 4); idx += 576) {
        int cell = idx % NCELL;
        int c = (idx / NCELL) * 4;
        int iy = cell / EXT, ix = cell % EXT;
        int gy = min(max(by + iy, 0), Hl - 1);
        int gx = min(max(bx + ix, 0), Wl - 1);
        const float* fp = fbase + (size_t)c * hw + (size_t)gy * Wl + gx;
        float4 v;
        v.x = fp[0];
        v.y = fp[hw];
        v.z = fp[2 * hw];
        v.w = fp[3 * hw];
        *reinterpret_cast<float4*>(&sfm[cell * CSTR + c]) = v;
    }
    // ---- stage gm transposed to [pq][c] ----
    const float* gbase = gmap + (size_t)iie * (C_CH * 9);
    for (int idx = tid; idx < C_CH * 9; idx += 576) {
        int c = idx / 9, pq2 = idx % 9;
        sg[pq2 * CSTR + c] = gbase[idx];
    }
    __syncthreads();

    // ---- compute: wave = pq, lane = 8x8 window cell ----
    int pq = wave;
    int a = lane >> 3, b = lane & 7;

    float x = cb[pq * 2 + 0] * scale;
    float y = cb[pq * 2 + 1] * scale;
    float x0f = floorf(x), y0f = floorf(y);
    float fx = x - x0f, fy = y - y0f;
    int offx = ((int)x0f - RADIUS) - bx;   // 0..2
    int offy = ((int)y0f - RADIUS) - by;   // 0..2

    int cell0 = (offy + a) * EXT + (offx + b);
    const float* fp_ = &sfm[cell0 * CSTR];
    const float* gp_ = &sg[pq * CSTR];

    float acc = 0.f;
#pragma unroll
    for (int c = 0; c < C_CH; c += 4) {
        float4 f = *reinterpret_cast<const float4*>(fp_ + c);
        float4 g = *reinterpret_cast<const float4*>(gp_ + c);
        acc += f.x * g.x + f.y * g.y + f.z * g.z + f.w * g.w;
    }

    float r01 = __shfl_down(acc, 1);
    float r10 = __shfl_down(acc, 8);
    float r11 = __shfl_down(acc, 9);

    if (a < 7 && b < 7) {
        float w00 = (1.f - fy) * (1.f - fx);
        float w01 = (1.f - fy) * fx;
        float w10 = fy * (1.f - fx);
        float w11 = fy * fx;
        float v = w00 * acc + w01 * r01 + w10 * r10 + w11 * r11;
        out[(size_t)e * 882 + (size_t)((a * 7 + b) * 9 + pq) * 2 + lvl] = v;
    }
}

extern "C" void kernel_launch(void* const* d_in, const int* in_sizes, int n_in,
                              void* d_out, int out_size, void* d_ws, size_t ws_size,
                              hipStream_t stream) {
    const float* fmap   = (const float*)d_in[0];
    const float* gmap   = (const float*)d_in[1];
    const float* coords = (const float*)d_in[2];
    const int* ii       = (const int*)d_in[3];
    const int* jj       = (const int*)d_in[4];
    float* out = (float*)d_out;
    float* fm1 = (float*)d_ws;   // N*C*H1*W1 floats = 9.83 MB

    int E = in_sizes[3];

    int total1 = N_FR * C_CH * H1 * W1;
    pool_kernel<<<(total1 + 255) / 256, 256, 0, stream>>>(fmap, fm1);
    corr_kernel<<<dim3(E, 2), 576, 0, stream>>>(fmap, fm1, gmap, coords, ii, jj, out);
}

// Round 3
// 263.691 us; speedup vs baseline: 9.5881x; 1.7459x over previous
//
#include <hip/hip_runtime.h>

#define RADIUS 3
#define C_CH 128
#define N_FR 16
#define H0 120
#define W0 160
#define H1 30
#define W1 40
#define EXT 10
#define NCELL 100
#define GSTR 132   // dword stride of sg rows (528B = 33*16B, 16B-aligned)
#define CSTRC 13   // dword stride of sC rows (odd -> spread banks)
#define FM1SZ (N_FR*C_CH*H1*W1)

// 4x4 average pool: fm0 [N,C,120,160] -> fm1 [N,C,30,40]
__global__ void pool_kernel(const float* __restrict__ fm0, float* __restrict__ fm1) {
    int idx = blockIdx.x * blockDim.x + threadIdx.x;
    int total = N_FR * C_CH * H1 * W1;
    if (idx >= total) return;
    int x = idx % W1;
    int y = (idx / W1) % H1;
    int nc = idx / (W1 * H1);
    const float* src = fm0 + ((size_t)nc * H0 + y * 4) * W0 + x * 4;
    float s = 0.f;
#pragma unroll
    for (int dy = 0; dy < 4; ++dy) {
        float4 v = *reinterpret_cast<const float4*>(src + dy * W0);
        s += v.x + v.y + v.z + v.w;
    }
    fm1[idx] = s * (1.f / 16.f);
}

__global__ void zero_kernel(int* cnt) {
    if (threadIdx.x < 32) cnt[threadIdx.x] = 0;   // cnt[16] + off[16]
}

__global__ void hist_kernel(const int* __restrict__ jj, int* __restrict__ cnt, int E) {
    __shared__ int h[N_FR];
    int tid = threadIdx.x;
    if (tid < N_FR) h[tid] = 0;
    __syncthreads();
    int e = blockIdx.x * blockDim.x + tid;
    if (e < E) atomicAdd(&h[jj[e]], 1);
    __syncthreads();
    if (tid < N_FR && h[tid] > 0) atomicAdd(&cnt[tid], h[tid]);
}

__global__ void scan_kernel(const int* __restrict__ cnt, int* __restrict__ off) {
    if (threadIdx.x == 0) {
        int s = 0;
        for (int f = 0; f < N_FR; ++f) { off[f] = s; s += cnt[f]; }
    }
}

__global__ void scatter_kernel(const int* __restrict__ jj, int* __restrict__ off,
                               int* __restrict__ perm, int E) {
    __shared__ int h[N_FR];
    __shared__ int base[N_FR];
    int tid = threadIdx.x;
    if (tid < N_FR) h[tid] = 0;
    __syncthreads();
    int e = blockIdx.x * blockDim.x + tid;
    int f = 0, rank = 0;
    if (e < E) {
        f = jj[e];
        rank = atomicAdd(&h[f], 1);
    }
    __syncthreads();
    if (tid < N_FR && h[tid] > 0) base[tid] = atomicAdd(&off[tid], h[tid]);
    __syncthreads();
    if (e < E) perm[base[f] + rank] = e;
}

// One block per (edge-slot, level). 128 threads: thread = one union-window cell.
__global__ __launch_bounds__(128) void corr_kernel(
        const float* __restrict__ fmap,   // [N,C,H0,W0]
        const float* __restrict__ fm1,    // [N,C,H1,W1]
        const float* __restrict__ gmap,   // [M,C,3,3]
        const float* __restrict__ coords, // [E,3,3,2]
        const int* __restrict__ ii,
        const int* __restrict__ jj,
        const int* __restrict__ perm,     // frame-sorted edge order (or null)
        float* __restrict__ out) {        // [E,7,7,3,3,2]
    __shared__ float sg[9 * GSTR];        // g transposed: [pq][c]
    __shared__ float sC[NCELL * CSTRC];   // C[cell][pq]

    int e = perm ? perm[blockIdx.x] : (int)blockIdx.x;
    int lvl = blockIdx.y;
    int tid = threadIdx.x;

    int Hl = lvl ? H1 : H0;
    int Wl = lvl ? W1 : W0;
    float scale = lvl ? 0.25f : 1.0f;
    const float* fm = lvl ? fm1 : fmap;

    int iie = ii[e];
    int jje = jj[e];
    const float* cb = coords + (size_t)e * 18;

    int bx = (int)floorf(cb[0] * scale) - RADIUS;
    int by = (int)floorf(cb[1] * scale) - RADIUS;

    // stage g transposed to [pq][c] (coalesced global read)
    const float* gbase = gmap + (size_t)iie * (C_CH * 9);
    for (int idx = tid; idx < C_CH * 9; idx += 128) {
        int c = idx / 9, pq = idx - c * 9;
        sg[pq * GSTR + c] = gbase[idx];
    }
    __syncthreads();

    // ---- per-cell channel contraction against all 9 patch positions ----
    if (tid < NCELL) {
        int iy = tid / EXT, ix = tid - iy * EXT;
        int gy = min(max(by + iy, 0), Hl - 1);
        int gx = min(max(bx + ix, 0), Wl - 1);
        int hw = Hl * Wl;
        const float* fp = fm + ((size_t)jje * C_CH) * hw + gy * Wl + gx;

        float acc[9];
#pragma unroll
        for (int pq = 0; pq < 9; ++pq) acc[pq] = 0.f;

#pragma unroll 2
        for (int c = 0; c < C_CH; c += 4) {
            float f0 = fp[0];
            float f1 = fp[hw];
            float f2 = fp[2 * hw];
            float f3 = fp[3 * hw];
            fp += 4 * hw;
#pragma unroll
            for (int pq = 0; pq < 9; ++pq) {
                float4 g4 = *reinterpret_cast<const float4*>(&sg[pq * GSTR + c]);
                acc[pq] += f0 * g4.x + f1 * g4.y + f2 * g4.z + f3 * g4.w;
            }
        }
#pragma unroll
        for (int pq = 0; pq < 9; ++pq) sC[tid * CSTRC + pq] = acc[pq];
    }
    __syncthreads();

    // ---- bilinear combine + store: 441 outputs ----
    for (int o = tid; o < 441; o += 128) {
        int pq = o % 9;
        int ab = o / 9;
        int a = ab / 7, b = ab - a * 7;
        float x = cb[pq * 2 + 0] * scale;
        float y = cb[pq * 2 + 1] * scale;
        float x0f = floorf(x), y0f = floorf(y);
        float fx = x - x0f, fy = y - y0f;
        int offx = ((int)x0f - RADIUS) - bx;
        int offy = ((int)y0f - RADIUS) - by;
        int cell = (offy + a) * EXT + (offx + b);
        float c00 = sC[cell * CSTRC + pq];
        float c01 = sC[(cell + 1) * CSTRC + pq];
        float c10 = sC[(cell + EXT) * CSTRC + pq];
        float c11 = sC[(cell + EXT + 1) * CSTRC + pq];
        float v = (1.f - fy) * (1.f - fx) * c00 + (1.f - fy) * fx * c01
                + fy * (1.f - fx) * c10 + fy * fx * c11;
        out[(size_t)e * 882 + (size_t)o * 2 + lvl] = v;
    }
}

extern "C" void kernel_launch(void* const* d_in, const int* in_sizes, int n_in,
                              void* d_out, int out_size, void* d_ws, size_t ws_size,
                              hipStream_t stream) {
    const float* fmap   = (const float*)d_in[0];
    const float* gmap   = (const float*)d_in[1];
    const float* coords = (const float*)d_in[2];
    const int* ii       = (const int*)d_in[3];
    const int* jj       = (const int*)d_in[4];
    float* out = (float*)d_out;
    float* fm1 = (float*)d_ws;                 // FM1SZ floats = 9.83 MB

    int E = in_sizes[3];
    size_t need = ((size_t)FM1SZ + 32 + (size_t)E) * 4;

    int total1 = N_FR * C_CH * H1 * W1;
    pool_kernel<<<(total1 + 255) / 256, 256, 0, stream>>>(fmap, fm1);

    int* perm = nullptr;
    if (ws_size >= need) {
        int* cnt = (int*)d_ws + FM1SZ;          // [16]
        int* off = cnt + N_FR;                  // [16]
        perm = off + N_FR;                      // [E]
        int nb = (E + 255) / 256;
        zero_kernel<<<1, 64, 0, stream>>>(cnt);
        hist_kernel<<<nb, 256, 0, stream>>>(jj, cnt, E);
        scan_kernel<<<1, 64, 0, stream>>>(cnt, off);
        scatter_kernel<<<nb, 256, 0, stream>>>(jj, off, perm, E);
    }

    corr_kernel<<<dim3(E, 2), 128, 0, stream>>>(fmap, fm1, gmap, coords, ii, jj, perm, out);
}